// Round 5
// baseline (10512.012 us; speedup 1.0000x reference)
//
#include <hip/hip_runtime.h>

// ---------------------------------------------------------------------------
// SharedOnlyMLP: out = (silu(x@(gw*gs).T) * (x@(uw*us).T)) @ (dw*ds).T
// Round 5: fused gate+up with FULL 256x256 coverage: per wave M=128, N=64
// for BOTH outputs (ag[8][4] + au[8][4] = 256 acc regs, ~335 total < 450
// spill line). 3-buffer 48KB LDS ring (A+Bg+Bu per buffer), BK=32 steps,
// 2 phases/step with 32 MFMA each, vmcnt(6) counted waits, proven XOR
// swizzle + VM-before-BAR publish discipline. Down-proj = r3 gemm256.
// ---------------------------------------------------------------------------

typedef __attribute__((ext_vector_type(8))) __bf16 bf16x8;
typedef __attribute__((ext_vector_type(4))) float f32x4;
typedef __attribute__((ext_vector_type(8))) unsigned short ushort8;

#define D_MODEL 4096
#define D_FF    11008
#define NTOK    8192

static __device__ __forceinline__ unsigned short f32_to_bf16(float f) {
    union { float f; unsigned u; } v; v.f = f;
    unsigned r = v.u + 0x7fffu + ((v.u >> 16) & 1u);   // round-nearest-even
    return (unsigned short)(r >> 16);
}
static __device__ __forceinline__ float bf16_to_f32(unsigned short s) {
    union { unsigned u; float f; } v; v.u = ((unsigned)s) << 16;
    return v.f;
}

static __device__ __forceinline__ void gload_lds16(const void* g, void* l) {
    __builtin_amdgcn_global_load_lds(
        (const __attribute__((address_space(1))) void*)g,
        (__attribute__((address_space(3))) void*)l, 16, 0, 0);
}

// ---- weight dequant: int32 (int8 values) * s[row] -> bf16, 8 elems/thread ----
__global__ __launch_bounds__(256)
void dequant_w_kernel(const int* __restrict__ w, const float* __restrict__ s,
                      unsigned short* __restrict__ out, int cols, long long total)
{
    long long i = ((long long)blockIdx.x * 256 + threadIdx.x) * 8;
    if (i >= total) return;
    float sc = s[(int)(i / cols)];
    int4 w0 = *(const int4*)(w + i);
    int4 w1 = *(const int4*)(w + i + 4);
    ushort8 r;
    r[0] = f32_to_bf16((float)w0.x * sc);
    r[1] = f32_to_bf16((float)w0.y * sc);
    r[2] = f32_to_bf16((float)w0.z * sc);
    r[3] = f32_to_bf16((float)w0.w * sc);
    r[4] = f32_to_bf16((float)w1.x * sc);
    r[5] = f32_to_bf16((float)w1.y * sc);
    r[6] = f32_to_bf16((float)w1.z * sc);
    r[7] = f32_to_bf16((float)w1.w * sc);
    *(ushort8*)(out + i) = r;
}

// ---- x: f32 -> bf16, 8 elems/thread ----
__global__ __launch_bounds__(256)
void cvt_x_kernel(const float* __restrict__ x, unsigned short* __restrict__ out,
                  long long total)
{
    long long i = ((long long)blockIdx.x * 256 + threadIdx.x) * 8;
    if (i >= total) return;
    float4 a = *(const float4*)(x + i);
    float4 b = *(const float4*)(x + i + 4);
    ushort8 r;
    r[0] = f32_to_bf16(a.x); r[1] = f32_to_bf16(a.y);
    r[2] = f32_to_bf16(a.z); r[3] = f32_to_bf16(a.w);
    r[4] = f32_to_bf16(b.x); r[5] = f32_to_bf16(b.y);
    r[6] = f32_to_bf16(b.z); r[7] = f32_to_bf16(b.w);
    *(ushort8*)(out + i) = r;
}

// ---------------------------------------------------------------------------
// Down-proj GEMM (r3 structure, PROVEN): C[M][N] = A[M][K] @ B[N][K]^T.
// ---------------------------------------------------------------------------
template<int MODE>
__global__ __launch_bounds__(512, 2)
void gemm256(const unsigned short* __restrict__ A,
             const unsigned short* __restrict__ B,
             void* __restrict__ C,
             const unsigned short* __restrict__ gateb,
             int M, int N, int K)
{
    extern __shared__ char smem[];
    const int tid = threadIdx.x;
    const int l   = tid & 63;
    const int w   = tid >> 6;
    const int wm  = w >> 2;
    const int wn  = w & 3;

    const int nbx  = gridDim.x;
    const int nwg  = nbx * gridDim.y;
    const int orig = blockIdx.y * nbx + blockIdx.x;
    const int cpx  = nwg >> 3;
    const int swz  = (orig & 7) * cpx + (orig >> 3);
    const int bn = swz % nbx, bm = swz / nbx;
    const int m0 = bm * 256, n0 = bn * 256;

    const int st_r = w * 16 + (l >> 2);
    const int st_c = (((l & 3) ^ ((l >> 3) & 3)) << 3);
    const unsigned short* gA = A + (size_t)(m0 + st_r) * K + st_c;
    const unsigned short* gB = B + (size_t)(n0 + st_r) * K + st_c;
    const size_t ld128 = (size_t)128 * K;

    const int s4v = l >> 4;
    const int rA = wm * 128 + (l & 15);
    const int rB = wn * 64  + (l & 15);
    const int offA = rA * 64 + ((s4v << 4) ^ (((rA >> 1) & 3) << 4));
    const int offB = 16384 + rB * 64 + ((s4v << 4) ^ (((rB >> 1) & 3) << 4));

    f32x4 acc[8][4] = {};
    bf16x8 af[4], bfr[4];

#define SBAR()  __builtin_amdgcn_sched_barrier(0)
#define BAR()   __builtin_amdgcn_s_barrier()
#define VM8()   asm volatile("s_waitcnt vmcnt(8)" ::: "memory")

#define STAGE_A(SS, NXT) do { \
    const unsigned short* p_ = gA + ((size_t)(SS) << 5); \
    gload_lds16(p_,         smem + (NXT) + (w << 10)); \
    gload_lds16(p_ + ld128, smem + (NXT) + 8192 + (w << 10)); } while (0)
#define STAGE_B(SS, NXT) do { \
    const unsigned short* p_ = gB + ((size_t)(SS) << 5); \
    gload_lds16(p_,         smem + (NXT) + 16384 + (w << 10)); \
    gload_lds16(p_ + ld128, smem + (NXT) + 16384 + 8192 + (w << 10)); } while (0)

#define MFMA16(MB) do { \
    _Pragma("unroll") \
    for (int mi_ = 0; mi_ < 4; ++mi_) { \
        _Pragma("unroll") \
        for (int ni_ = 0; ni_ < 4; ++ni_) { \
            acc[(MB) + mi_][ni_] = __builtin_amdgcn_mfma_f32_16x16x32_bf16( \
                af[mi_], bfr[ni_], acc[(MB) + mi_][ni_], 0, 0, 0); \
        } } } while (0)

#define STEP(CUR, NXT, SS) do { \
    af[0]  = *(const bf16x8*)(smem + (CUR) + offA); \
    af[1]  = *(const bf16x8*)(smem + (CUR) + offA + 1024); \
    af[2]  = *(const bf16x8*)(smem + (CUR) + offA + 2048); \
    af[3]  = *(const bf16x8*)(smem + (CUR) + offA + 3072); \
    bfr[0] = *(const bf16x8*)(smem + (CUR) + offB); \
    bfr[1] = *(const bf16x8*)(smem + (CUR) + offB + 1024); \
    bfr[2] = *(const bf16x8*)(smem + (CUR) + offB + 2048); \
    bfr[3] = *(const bf16x8*)(smem + (CUR) + offB + 3072); \
    STAGE_A(SS, NXT); \
    SBAR(); BAR(); \
    __builtin_amdgcn_s_setprio(1); MFMA16(0); __builtin_amdgcn_s_setprio(0); \
    SBAR(); BAR(); \
    af[0] = *(const bf16x8*)(smem + (CUR) + offA + 4096); \
    af[1] = *(const bf16x8*)(smem + (CUR) + offA + 5120); \
    af[2] = *(const bf16x8*)(smem + (CUR) + offA + 6144); \
    af[3] = *(const bf16x8*)(smem + (CUR) + offA + 7168); \
    STAGE_B(SS, NXT); \
    SBAR(); BAR(); \
    __builtin_amdgcn_s_setprio(1); MFMA16(4); __builtin_amdgcn_s_setprio(0); \
    VM8(); SBAR(); BAR(); \
} while (0)

    STAGE_A(0, 0);      STAGE_B(0, 0);
    STAGE_A(1, 32768);  STAGE_B(1, 32768);
    STAGE_A(2, 65536);  STAGE_B(2, 65536);
    asm volatile("s_waitcnt vmcnt(8)" ::: "memory");
    SBAR(); BAR();

    const int T = K >> 5;
    #pragma unroll 1
    for (int s = 0; s < T; s += 4) {
        int s3 = s + 3; if (s3 >= T) s3 -= T;
        int s4 = s + 4; if (s4 >= T) s4 -= T;
        int s5 = s + 5; if (s5 >= T) s5 -= T;
        int s6 = s + 6; if (s6 >= T) s6 -= T;
        STEP(0,     98304, s3);
        STEP(32768, 0,     s4);
        STEP(65536, 32768, s5);
        STEP(98304, 65536, s6);
    }
    asm volatile("s_waitcnt vmcnt(0)" ::: "memory");

    const int er = (l >> 4) * 4;
    const int ec = l & 15;
    #pragma unroll
    for (int mi = 0; mi < 8; ++mi) {
        #pragma unroll
        for (int ni = 0; ni < 4; ++ni) {
            #pragma unroll
            for (int q = 0; q < 4; ++q) {
                int row = m0 + wm * 128 + mi * 16 + er + q;
                int col = n0 + wn * 64  + ni * 16 + ec;
                size_t idx = (size_t)row * N + col;
                float v = acc[mi][ni][q];
                if (MODE == 0) {
                    ((unsigned short*)C)[idx] = f32_to_bf16(v);
                } else if (MODE == 1) {
                    float g   = bf16_to_f32(gateb[idx]);
                    float sig = 1.0f / (1.0f + __expf(-g));
                    ((unsigned short*)C)[idx] = f32_to_bf16(g * sig * v);
                } else {
                    ((float*)C)[idx] = v;
                }
            }
        }
    }
#undef STEP
#undef MFMA16
#undef STAGE_A
#undef STAGE_B
#undef VM8
#undef BAR
#undef SBAR
}

// ---------------------------------------------------------------------------
// FUSED gate+up, full 256x256 tile: per wave M=128, N=64 for both outputs.
// LDS buffer (48 KiB): A [256][32] at +0, Bg [256][32] at +16384,
// Bu [256][32] at +32768. 3-buffer ring (144 KiB); stage step s+2 during
// step s; vmcnt(6) once per step. 2 phases/step, 32 MFMA each.
// ---------------------------------------------------------------------------
__global__ __launch_bounds__(512, 2)
void gemm_fused(const unsigned short* __restrict__ A,
                const unsigned short* __restrict__ Bg,
                const unsigned short* __restrict__ Bu,
                unsigned short* __restrict__ H,
                int M, int N, int K)
{
    extern __shared__ char smem[];
    const int tid = threadIdx.x;
    const int l   = tid & 63;
    const int w   = tid >> 6;
    const int wm  = w >> 2;          // 0..1
    const int wn  = w & 3;           // 0..3

    const int nbx  = gridDim.x;
    const int nwg  = nbx * gridDim.y;
    const int orig = blockIdx.y * nbx + blockIdx.x;
    const int cpx  = nwg >> 3;
    const int swz  = (orig & 7) * cpx + (orig >> 3);
    const int bn = swz % nbx, bm = swz / nbx;
    const int m0 = bm * 256, n0 = bn * 256;

    const int st_r = w * 16 + (l >> 2);
    const int st_c = (((l & 3) ^ ((l >> 3) & 3)) << 3);
    const unsigned short* gA = A  + (size_t)(m0 + st_r) * K + st_c;
    const unsigned short* gG = Bg + (size_t)(n0 + st_r) * K + st_c;
    const unsigned short* gU = Bu + (size_t)(n0 + st_r) * K + st_c;
    const size_t ld128 = (size_t)128 * K;

    const int s4v = l >> 4;
    const int rA = wm * 128 + (l & 15);
    const int rB = wn * 64  + (l & 15);          // per-wave N=64 (full coverage)
    const int offA  = rA * 64 + ((s4v << 4) ^ (((rA >> 1) & 3) << 4));
    const int offBg = 16384 + rB * 64 + ((s4v << 4) ^ (((rB >> 1) & 3) << 4));
    const int offBu = offBg + 16384;

    f32x4 ag[8][4] = {};
    f32x4 au[8][4] = {};
    bf16x8 af[4], bgv[4], buv[4];

#define SBAR()  __builtin_amdgcn_sched_barrier(0)
#define BAR()   __builtin_amdgcn_s_barrier()
#define VM6()   asm volatile("s_waitcnt vmcnt(6)" ::: "memory")

#define FSTAGE_A(SS, NXT) do { \
    const unsigned short* p_ = gA + ((size_t)(SS) << 5); \
    gload_lds16(p_,         smem + (NXT) + (w << 10)); \
    gload_lds16(p_ + ld128, smem + (NXT) + 8192 + (w << 10)); } while (0)
#define FSTAGE_G(SS, NXT) do { \
    const unsigned short* p_ = gG + ((size_t)(SS) << 5); \
    gload_lds16(p_,         smem + (NXT) + 16384 + (w << 10)); \
    gload_lds16(p_ + ld128, smem + (NXT) + 16384 + 8192 + (w << 10)); } while (0)
#define FSTAGE_U(SS, NXT) do { \
    const unsigned short* p_ = gU + ((size_t)(SS) << 5); \
    gload_lds16(p_,         smem + (NXT) + 32768 + (w << 10)); \
    gload_lds16(p_ + ld128, smem + (NXT) + 32768 + 8192 + (w << 10)); } while (0)

// 32 MFMA: rows MB..MB+3, both gate and up, all 4 ni
#define FMFMA32(MB) do { \
    _Pragma("unroll") \
    for (int mi_ = 0; mi_ < 4; ++mi_) { \
        _Pragma("unroll") \
        for (int ni_ = 0; ni_ < 4; ++ni_) { \
            ag[(MB) + mi_][ni_] = __builtin_amdgcn_mfma_f32_16x16x32_bf16( \
                af[mi_], bgv[ni_], ag[(MB) + mi_][ni_], 0, 0, 0); \
            au[(MB) + mi_][ni_] = __builtin_amdgcn_mfma_f32_16x16x32_bf16( \
                af[mi_], buv[ni_], au[(MB) + mi_][ni_], 0, 0, 0); \
        } } } while (0)

// One BK=32 step = 2 phases, 32 MFMA each; stages step SS into buffer NXT.
#define FSTEP(CUR, NXT, SS) do { \
    /* phase 1: af[0-3] + bgv[0-3] + buv[0-3] (12 ds_reads), stage A(SS) */ \
    af[0]  = *(const bf16x8*)(smem + (CUR) + offA); \
    af[1]  = *(const bf16x8*)(smem + (CUR) + offA + 1024); \
    af[2]  = *(const bf16x8*)(smem + (CUR) + offA + 2048); \
    af[3]  = *(const bf16x8*)(smem + (CUR) + offA + 3072); \
    bgv[0] = *(const bf16x8*)(smem + (CUR) + offBg); \
    bgv[1] = *(const bf16x8*)(smem + (CUR) + offBg + 1024); \
    bgv[2] = *(const bf16x8*)(smem + (CUR) + offBg + 2048); \
    bgv[3] = *(const bf16x8*)(smem + (CUR) + offBg + 3072); \
    buv[0] = *(const bf16x8*)(smem + (CUR) + offBu); \
    buv[1] = *(const bf16x8*)(smem + (CUR) + offBu + 1024); \
    buv[2] = *(const bf16x8*)(smem + (CUR) + offBu + 2048); \
    buv[3] = *(const bf16x8*)(smem + (CUR) + offBu + 3072); \
    FSTAGE_A(SS, NXT); \
    SBAR(); BAR(); \
    __builtin_amdgcn_s_setprio(1); FMFMA32(0); __builtin_amdgcn_s_setprio(0); \
    SBAR(); BAR(); \
    /* phase 2: af[4-7] (4 ds_reads), stage Bg(SS)+Bu(SS) */ \
    af[0] = *(const bf16x8*)(smem + (CUR) + offA + 4096); \
    af[1] = *(const bf16x8*)(smem + (CUR) + offA + 5120); \
    af[2] = *(const bf16x8*)(smem + (CUR) + offA + 6144); \
    af[3] = *(const bf16x8*)(smem + (CUR) + offA + 7168); \
    FSTAGE_G(SS, NXT); FSTAGE_U(SS, NXT); \
    SBAR(); BAR(); \
    __builtin_amdgcn_s_setprio(1); FMFMA32(4); __builtin_amdgcn_s_setprio(0); \
    VM6(); SBAR(); BAR(); \
} while (0)

    const int BUF = 49152;

    // prologue: stage steps 0,1 (6 loads each); wait step 0's 6
    FSTAGE_A(0, 0);   FSTAGE_G(0, 0);   FSTAGE_U(0, 0);
    FSTAGE_A(1, BUF); FSTAGE_G(1, BUF); FSTAGE_U(1, BUF);
    VM6(); SBAR(); BAR();

    const int T = K >> 5;            // 128
    int cur = 0, nxt = 2 * BUF;
    #pragma unroll 1
    for (int s = 0; s < T; ++s) {
        int ss = s + 2; if (ss >= T) ss -= T;   // wrapped restage (harmless)
        FSTEP(cur, nxt, ss);
        cur += BUF; if (cur == 3 * BUF) cur = 0;
        nxt += BUF; if (nxt == 3 * BUF) nxt = 0;
    }
    asm volatile("s_waitcnt vmcnt(0)" ::: "memory");   // drain dangling writes

    // epilogue: h = silu(g) * u, full 256x256 coverage
    const int er = (l >> 4) * 4;
    const int ec = l & 15;
    #pragma unroll
    for (int mi = 0; mi < 8; ++mi) {
        #pragma unroll
        for (int ni = 0; ni < 4; ++ni) {
            #pragma unroll
            for (int q = 0; q < 4; ++q) {
                int row = m0 + wm * 128 + mi * 16 + er + q;
                int col = n0 + wn * 64  + ni * 16 + ec;
                float g = ag[mi][ni][q];
                float u = au[mi][ni][q];
                float sig = 1.0f / (1.0f + __expf(-g));
                H[(size_t)row * N + col] = f32_to_bf16(g * sig * u);
            }
        }
    }
#undef FSTEP
#undef FMFMA32
#undef FSTAGE_A
#undef FSTAGE_G
#undef FSTAGE_U
#undef VM6
#undef BAR
#undef SBAR
}

extern "C" void kernel_launch(void* const* d_in, const int* in_sizes, int n_in,
                              void* d_out, int out_size, void* d_ws, size_t ws_size,
                              hipStream_t stream)
{
    const float* x  = (const float*)d_in[0];
    const int*   gw = (const int*)  d_in[1];
    const float* gs = (const float*)d_in[2];
    const int*   uw = (const int*)  d_in[3];
    const float* us = (const float*)d_in[4];
    const int*   dw = (const int*)  d_in[5];
    const float* dsc= (const float*)d_in[6];

    char* ws = (char*)d_ws;
    unsigned short* Xb = (unsigned short*)ws;  ws += (size_t)NTOK  * D_MODEL * 2;
    unsigned short* Wg = (unsigned short*)ws;  ws += (size_t)D_FF  * D_MODEL * 2;
    unsigned short* Wu = (unsigned short*)ws;  ws += (size_t)D_FF  * D_MODEL * 2;
    unsigned short* Wd = (unsigned short*)ws;  ws += (size_t)D_MODEL * D_FF * 2;
    unsigned short* H  = (unsigned short*)ws;  // NTOK * D_FF bf16

    const long long wtot = (long long)D_FF * D_MODEL;
    const long long xtot = (long long)NTOK * D_MODEL;

    hipFuncSetAttribute(reinterpret_cast<const void*>(gemm_fused),
                        hipFuncAttributeMaxDynamicSharedMemorySize, 147456);
    hipFuncSetAttribute(reinterpret_cast<const void*>(gemm256<2>),
                        hipFuncAttributeMaxDynamicSharedMemorySize, 131072);

    dequant_w_kernel<<<(int)(wtot / 2048), 256, 0, stream>>>(gw, gs,  Wg, D_MODEL, wtot);
    dequant_w_kernel<<<(int)(wtot / 2048), 256, 0, stream>>>(uw, us,  Wu, D_MODEL, wtot);
    dequant_w_kernel<<<(int)(wtot / 2048), 256, 0, stream>>>(dw, dsc, Wd, D_FF,    wtot);
    cvt_x_kernel    <<<(int)(xtot / 2048), 256, 0, stream>>>(x, Xb, xtot);

    // fused gate+up: H = silu(Xb@Wg^T) * (Xb@Wu^T)
    dim3 gf(D_FF / 256, NTOK / 256);     // 43 x 32 = 1376 blocks (%8==0)
    gemm_fused<<<gf, 512, 147456, stream>>>(Xb, Wg, Wu, H, NTOK, D_FF, D_MODEL);

    // out = H @ Wd^T -> f32
    dim3 g3(D_MODEL / 256, NTOK / 256);  // 16 x 32 = 512 blocks (%8==0)
    gemm256<2><<<g3, 512, 131072, stream>>>(H, Wd, d_out, nullptr, NTOK, D_MODEL, D_FF);
}

// Round 6
// 1650.561 us; speedup vs baseline: 6.3688x; 6.3688x over previous
//
#include <hip/hip_runtime.h>

// ---------------------------------------------------------------------------
// SharedOnlyMLP r6: int8 path for gate/up GEMMs.
//   x -> per-row int8 (scale xs[row]); weights already int8 (exact repack).
//   gate/up: i8 MFMA (mfma_i32_16x16x64_i8), 256x256 tile, BK=64 steps of
//   2 phases (16 MFMA each), 4-buffer 32KB LDS ring, vmcnt(4) counted waits,
//   r2-proven XOR swizzle (identical byte geometry). Epilogue applies
//   gs[col]*xs[row] (and SiLU fuse for up, in-place H over gate).
//   down-proj: r2-proven bf16 gemm256 (BK=64, 2-buffer, 4 phases).
// ---------------------------------------------------------------------------

typedef __attribute__((ext_vector_type(8))) __bf16 bf16x8;
typedef __attribute__((ext_vector_type(4))) float f32x4;
typedef __attribute__((ext_vector_type(8))) unsigned short ushort8;
typedef __attribute__((ext_vector_type(4))) int i32x4;

#define D_MODEL 4096
#define D_FF    11008
#define NTOK    8192

static __device__ __forceinline__ unsigned short f32_to_bf16(float f) {
    union { float f; unsigned u; } v; v.f = f;
    unsigned r = v.u + 0x7fffu + ((v.u >> 16) & 1u);
    return (unsigned short)(r >> 16);
}
static __device__ __forceinline__ float bf16_to_f32(unsigned short s) {
    union { unsigned u; float f; } v; v.u = ((unsigned)s) << 16;
    return v.f;
}
static __device__ __forceinline__ void gload_lds16(const void* g, void* l) {
    __builtin_amdgcn_global_load_lds(
        (const __attribute__((address_space(1))) void*)g,
        (__attribute__((address_space(3))) void*)l, 16, 0, 0);
}

// ---- pack int32 (int8 values) -> int8, exact. 8 elems/thread ----
__global__ __launch_bounds__(256)
void pack_w_kernel(const int* __restrict__ w, signed char* __restrict__ out,
                   long long total)
{
    long long i = ((long long)blockIdx.x * 256 + threadIdx.x) * 8;
    if (i >= total) return;
    int4 w0 = *(const int4*)(w + i);
    int4 w1 = *(const int4*)(w + i + 4);
    union { signed char c[8]; unsigned long long u; } r;
    r.c[0] = (signed char)w0.x; r.c[1] = (signed char)w0.y;
    r.c[2] = (signed char)w0.z; r.c[3] = (signed char)w0.w;
    r.c[4] = (signed char)w1.x; r.c[5] = (signed char)w1.y;
    r.c[6] = (signed char)w1.z; r.c[7] = (signed char)w1.w;
    *(unsigned long long*)(out + i) = r.u;
}

// ---- weight dequant (for down-proj): int32 * s[row] -> bf16 ----
__global__ __launch_bounds__(256)
void dequant_w_kernel(const int* __restrict__ w, const float* __restrict__ s,
                      unsigned short* __restrict__ out, int cols, long long total)
{
    long long i = ((long long)blockIdx.x * 256 + threadIdx.x) * 8;
    if (i >= total) return;
    float sc = s[(int)(i / cols)];
    int4 w0 = *(const int4*)(w + i);
    int4 w1 = *(const int4*)(w + i + 4);
    ushort8 r;
    r[0] = f32_to_bf16((float)w0.x * sc);
    r[1] = f32_to_bf16((float)w0.y * sc);
    r[2] = f32_to_bf16((float)w0.z * sc);
    r[3] = f32_to_bf16((float)w0.w * sc);
    r[4] = f32_to_bf16((float)w1.x * sc);
    r[5] = f32_to_bf16((float)w1.y * sc);
    r[6] = f32_to_bf16((float)w1.z * sc);
    r[7] = f32_to_bf16((float)w1.w * sc);
    *(ushort8*)(out + i) = r;
}

// ---- x: f32 -> per-row int8 + scale. 1 block / row, 16 elems/thread ----
__global__ __launch_bounds__(256)
void quant_x_kernel(const float* __restrict__ x, signed char* __restrict__ xq,
                    float* __restrict__ xs)
{
    __shared__ float red[4];
    const int row = blockIdx.x;
    const int t   = threadIdx.x;
    const float* xr = x + (size_t)row * D_MODEL;
    float4 v0 = *(const float4*)(xr + t * 16);
    float4 v1 = *(const float4*)(xr + t * 16 + 4);
    float4 v2 = *(const float4*)(xr + t * 16 + 8);
    float4 v3 = *(const float4*)(xr + t * 16 + 12);
    float m = fabsf(v0.x);
    m = fmaxf(m, fabsf(v0.y)); m = fmaxf(m, fabsf(v0.z)); m = fmaxf(m, fabsf(v0.w));
    m = fmaxf(m, fabsf(v1.x)); m = fmaxf(m, fabsf(v1.y)); m = fmaxf(m, fabsf(v1.z)); m = fmaxf(m, fabsf(v1.w));
    m = fmaxf(m, fabsf(v2.x)); m = fmaxf(m, fabsf(v2.y)); m = fmaxf(m, fabsf(v2.z)); m = fmaxf(m, fabsf(v2.w));
    m = fmaxf(m, fabsf(v3.x)); m = fmaxf(m, fabsf(v3.y)); m = fmaxf(m, fabsf(v3.z)); m = fmaxf(m, fabsf(v3.w));
    #pragma unroll
    for (int o = 32; o > 0; o >>= 1) m = fmaxf(m, __shfl_xor(m, o));
    if ((t & 63) == 0) red[t >> 6] = m;
    __syncthreads();
    m = fmaxf(fmaxf(red[0], red[1]), fmaxf(red[2], red[3]));
    m = fmaxf(m, 1e-20f);
    const float inv = 127.0f / m;
    if (t == 0) xs[row] = m / 127.0f;
    union { signed char c[16]; int4 i; } r;
    #pragma unroll
    for (int j = 0; j < 4; ++j) {
        float4 v = (j == 0) ? v0 : (j == 1) ? v1 : (j == 2) ? v2 : v3;
        r.c[j*4+0] = (signed char)(int)rintf(fminf(fmaxf(v.x*inv,-127.f),127.f));
        r.c[j*4+1] = (signed char)(int)rintf(fminf(fmaxf(v.y*inv,-127.f),127.f));
        r.c[j*4+2] = (signed char)(int)rintf(fminf(fmaxf(v.z*inv,-127.f),127.f));
        r.c[j*4+3] = (signed char)(int)rintf(fminf(fmaxf(v.w*inv,-127.f),127.f));
    }
    *(int4*)(xq + (size_t)row * D_MODEL + t * 16) = r.i;
}

// ---------------------------------------------------------------------------
// i8 GEMM: C = A[M][K]i8 @ B[N][K]i8^T, scaled by xs[row]*cs[col].
// 256x256 tile, 8 waves 2Mx4N, per-wave 128x64, acc[8][4] of 16x16x64 i8.
// LDS buffer 32KB: A [256 rows][64 B] at +0, B at +16384; 4-buffer ring.
// Swizzle (bytes, identical to r2): chunk16 ^= ((row>>1)&3), both sides.
// Step = BK=64 = 2 phases x 16 MFMA; stage s+2 during s; vmcnt(4)/step.
// MODE 0: C=bf16 gate. MODE 1: h=silu(gate)*up -> bf16 (in-place over gate).
// ---------------------------------------------------------------------------
template<int MODE>
__global__ __launch_bounds__(512, 2)
void gemm_i8(const signed char* __restrict__ A,
             const signed char* __restrict__ B,
             unsigned short* __restrict__ C,
             const unsigned short* __restrict__ gateb,
             const float* __restrict__ xs,
             const float* __restrict__ cs,
             int M, int N, int K)
{
    extern __shared__ char smem[];
    const int tid = threadIdx.x;
    const int l   = tid & 63;
    const int w   = tid >> 6;
    const int wm  = w >> 2;
    const int wn  = w & 3;

    const int nbx  = gridDim.x;
    const int nwg  = nbx * gridDim.y;
    const int orig = blockIdx.y * nbx + blockIdx.x;
    const int cpx  = nwg >> 3;
    const int swz  = (orig & 7) * cpx + (orig >> 3);
    const int bn = swz % nbx, bm = swz / nbx;
    const int m0 = bm * 256, n0 = bn * 256;

    // staging: thread t -> row t>>2, 16-B chunk (t&3), source pre-swizzled
    const int st_r = tid >> 2;
    const int st_c = ((tid & 3) ^ ((st_r >> 1) & 3)) << 4;   // bytes
    const signed char* gA = A + (size_t)(m0 + st_r) * K + st_c;
    const signed char* gB = B + (size_t)(n0 + st_r) * K + st_c;
    const size_t ld128 = (size_t)128 * K;

    // ds_read offsets (swizzled), row stride 64 B
    const int s4v = l >> 4;
    const int rA = wm * 128 + (l & 15);
    const int rB = wn * 64  + (l & 15);
    const int offA = rA * 64 + ((s4v << 4) ^ (((rA >> 1) & 3) << 4));
    const int offB = 16384 + rB * 64 + ((s4v << 4) ^ (((rB >> 1) & 3) << 4));

    i32x4 acc[8][4] = {};
    i32x4 af[4], bfr[4];

#define SBAR()  __builtin_amdgcn_sched_barrier(0)
#define BAR()   __builtin_amdgcn_s_barrier()
#define VM4()   asm volatile("s_waitcnt vmcnt(4)" ::: "memory")

#define ST_A8(SS, NXT) do { \
    const signed char* p_ = gA + ((size_t)(SS) << 6); \
    gload_lds16(p_,         smem + (NXT) + (tid & 0xFFC0 ? 0 : 0) + (w << 10)); \
    gload_lds16(p_ + ld128, smem + (NXT) + 8192 + (w << 10)); } while (0)
#define ST_B8(SS, NXT) do { \
    const signed char* p_ = gB + ((size_t)(SS) << 6); \
    gload_lds16(p_,         smem + (NXT) + 16384 + (w << 10)); \
    gload_lds16(p_ + ld128, smem + (NXT) + 16384 + 8192 + (w << 10)); } while (0)

#define MFMA16_I8(MB) do { \
    _Pragma("unroll") \
    for (int mi_ = 0; mi_ < 4; ++mi_) { \
        _Pragma("unroll") \
        for (int ni_ = 0; ni_ < 4; ++ni_) { \
            acc[(MB) + mi_][ni_] = __builtin_amdgcn_mfma_i32_16x16x64_i8( \
                af[mi_], bfr[ni_], acc[(MB) + mi_][ni_], 0, 0, 0); \
        } } } while (0)

// Step s (BK=64): read buf CUR, stage step SS=s+2 into NXT. 2 phases.
#define STEP8(CUR, NXT, SS) do { \
    af[0]  = *(const i32x4*)(smem + (CUR) + offA); \
    af[1]  = *(const i32x4*)(smem + (CUR) + offA + 1024); \
    af[2]  = *(const i32x4*)(smem + (CUR) + offA + 2048); \
    af[3]  = *(const i32x4*)(smem + (CUR) + offA + 3072); \
    bfr[0] = *(const i32x4*)(smem + (CUR) + offB); \
    bfr[1] = *(const i32x4*)(smem + (CUR) + offB + 1024); \
    bfr[2] = *(const i32x4*)(smem + (CUR) + offB + 2048); \
    bfr[3] = *(const i32x4*)(smem + (CUR) + offB + 3072); \
    ST_A8(SS, NXT); \
    SBAR(); BAR(); \
    __builtin_amdgcn_s_setprio(1); MFMA16_I8(0); __builtin_amdgcn_s_setprio(0); \
    SBAR(); BAR(); \
    af[0] = *(const i32x4*)(smem + (CUR) + offA + 4096); \
    af[1] = *(const i32x4*)(smem + (CUR) + offA + 5120); \
    af[2] = *(const i32x4*)(smem + (CUR) + offA + 6144); \
    af[3] = *(const i32x4*)(smem + (CUR) + offA + 7168); \
    ST_B8(SS, NXT); \
    SBAR(); BAR(); \
    __builtin_amdgcn_s_setprio(1); MFMA16_I8(4); __builtin_amdgcn_s_setprio(0); \
    VM4(); SBAR(); BAR(); \
} while (0)

    // prologue: stage steps 0,1 into bufs 0,1; wait step 0 (oldest 4)
    ST_A8(0, 0);      ST_B8(0, 0);
    ST_A8(1, 32768);  ST_B8(1, 32768);
    VM4(); SBAR(); BAR();

    const int T = K >> 6;            // 64 steps (K=4096); T%4==0
    #pragma unroll 1
    for (int s = 0; s < T; s += 4) {
        int s2 = s + 2; if (s2 >= T) s2 -= T;
        int s3 = s + 3; if (s3 >= T) s3 -= T;
        int s4 = s + 4; if (s4 >= T) s4 -= T;
        int s5 = s + 5; if (s5 >= T) s5 -= T;
        STEP8(0,     65536, s2);
        STEP8(32768, 98304, s3);
        STEP8(65536, 0,     s4);
        STEP8(98304, 32768, s5);
    }
    asm volatile("s_waitcnt vmcnt(0)" ::: "memory");

    // epilogue: D col=l&15, row=(l>>4)*4+q (dtype-independent layout)
    const int er = (l >> 4) * 4;
    const int ec = l & 15;
    #pragma unroll
    for (int mi = 0; mi < 8; ++mi) {
        const int rowb = m0 + wm * 128 + mi * 16 + er;
        const float4 xsv = *(const float4*)(xs + rowb);
        #pragma unroll
        for (int ni = 0; ni < 4; ++ni) {
            const int col = n0 + wn * 64 + ni * 16 + ec;
            const float csc = cs[col];
            #pragma unroll
            for (int q = 0; q < 4; ++q) {
                const int row = rowb + q;
                const float xsc = (q == 0) ? xsv.x : (q == 1) ? xsv.y
                                 : (q == 2) ? xsv.z : xsv.w;
                size_t idx = (size_t)row * N + col;
                float v = (float)acc[mi][ni][q] * csc * xsc;
                if (MODE == 0) {
                    C[idx] = f32_to_bf16(v);
                } else {
                    float g   = bf16_to_f32(gateb[idx]);
                    float sig = 1.0f / (1.0f + __expf(-g));
                    C[idx] = f32_to_bf16(g * sig * v);
                }
            }
        }
    }
#undef STEP8
#undef MFMA16_I8
#undef ST_A8
#undef ST_B8
#undef VM4
#undef BAR
#undef SBAR
}

// ---------------------------------------------------------------------------
// Down-proj bf16 GEMM — r2-proven structure (BK=64 2-buffer, 4 phases/tile).
// ---------------------------------------------------------------------------
template<int MODE>
__global__ __launch_bounds__(512, 2)
void gemm256(const unsigned short* __restrict__ A,
             const unsigned short* __restrict__ B,
             void* __restrict__ C,
             int M, int N, int K)
{
    extern __shared__ char smem[];
    const int tid = threadIdx.x;
    const int l   = tid & 63;
    const int w   = tid >> 6;
    const int wm  = w >> 2;
    const int wn  = w & 3;

    const int nbx  = gridDim.x;
    const int nwg  = nbx * gridDim.y;
    const int orig = blockIdx.y * nbx + blockIdx.x;
    const int cpx  = nwg >> 3;
    const int swz  = (orig & 7) * cpx + (orig >> 3);
    const int bn = swz % nbx, bm = swz / nbx;
    const int m0 = bm * 256, n0 = bn * 256;

    const int st_r = w * 16 + (l >> 2);
    const int st_c = (((l & 3) ^ ((l >> 3) & 3)) << 3);
    const unsigned short* gA = A + (size_t)(m0 + st_r) * K + st_c;
    const unsigned short* gB = B + (size_t)(n0 + st_r) * K + st_c;
    const size_t ld128 = (size_t)128 * K;

    const int s4v = l >> 4;
    const int rA = wm * 128 + (l & 15);
    const int rB = wn * 64  + (l & 15);
    const int offA = rA * 64 + ((s4v << 4) ^ (((rA >> 1) & 3) << 4));
    const int offB = 32768 + rB * 64 + ((s4v << 4) ^ (((rB >> 1) & 3) << 4));

    f32x4 acc[8][4] = {};
    bf16x8 af[4], bfr[4];

#define SBAR()  __builtin_amdgcn_sched_barrier(0)
#define BAR()   __builtin_amdgcn_s_barrier()
#define VM4()   asm volatile("s_waitcnt vmcnt(4)" ::: "memory")
#define STAGE2(SRC, LOFF) do { \
    gload_lds16((SRC), smem + (LOFF) + (w << 10)); \
    gload_lds16((SRC) + ld128, smem + (LOFF) + 8192 + (w << 10)); } while (0)

#define MFMA16(MB) do { \
    _Pragma("unroll") \
    for (int mi_ = 0; mi_ < 4; ++mi_) { \
        _Pragma("unroll") \
        for (int ni_ = 0; ni_ < 4; ++ni_) { \
            acc[(MB) + mi_][ni_] = __builtin_amdgcn_mfma_f32_16x16x32_bf16( \
                af[mi_], bfr[ni_], acc[(MB) + mi_][ni_], 0, 0, 0); \
        } } } while (0)

#define TILE(DB, KTN) do { \
    const int CB = (DB) * 65536; \
    const int PB = ((DB) ^ 1) * 65536; \
    const unsigned short* sA = gA + ((size_t)(KTN) << 6); \
    const unsigned short* sB = gB + ((size_t)(KTN) << 6); \
    af[0]  = *(const bf16x8*)(smem + CB + offA); \
    af[1]  = *(const bf16x8*)(smem + CB + offA + 1024); \
    af[2]  = *(const bf16x8*)(smem + CB + offA + 2048); \
    af[3]  = *(const bf16x8*)(smem + CB + offA + 3072); \
    bfr[0] = *(const bf16x8*)(smem + CB + offB); \
    bfr[1] = *(const bf16x8*)(smem + CB + offB + 1024); \
    bfr[2] = *(const bf16x8*)(smem + CB + offB + 2048); \
    bfr[3] = *(const bf16x8*)(smem + CB + offB + 3072); \
    STAGE2(sA, PB); \
    SBAR(); BAR(); \
    __builtin_amdgcn_s_setprio(1); MFMA16(0); __builtin_amdgcn_s_setprio(0); \
    SBAR(); BAR(); \
    af[0] = *(const bf16x8*)(smem + CB + offA + 4096); \
    af[1] = *(const bf16x8*)(smem + CB + offA + 5120); \
    af[2] = *(const bf16x8*)(smem + CB + offA + 6144); \
    af[3] = *(const bf16x8*)(smem + CB + offA + 7168); \
    STAGE2(sB, PB + 32768); \
    SBAR(); BAR(); \
    __builtin_amdgcn_s_setprio(1); MFMA16(4); __builtin_amdgcn_s_setprio(0); \
    VM4(); SBAR(); BAR(); \
    af[0]  = *(const bf16x8*)(smem + CB + 16384 + offA); \
    af[1]  = *(const bf16x8*)(smem + CB + 16384 + offA + 1024); \
    af[2]  = *(const bf16x8*)(smem + CB + 16384 + offA + 2048); \
    af[3]  = *(const bf16x8*)(smem + CB + 16384 + offA + 3072); \
    bfr[0] = *(const bf16x8*)(smem + CB + 16384 + offB); \
    bfr[1] = *(const bf16x8*)(smem + CB + 16384 + offB + 1024); \
    bfr[2] = *(const bf16x8*)(smem + CB + 16384 + offB + 2048); \
    bfr[3] = *(const bf16x8*)(smem + CB + 16384 + offB + 3072); \
    STAGE2(sA + 32, PB + 16384); \
    SBAR(); BAR(); \
    __builtin_amdgcn_s_setprio(1); MFMA16(0); __builtin_amdgcn_s_setprio(0); \
    SBAR(); BAR(); \
    af[0] = *(const bf16x8*)(smem + CB + 16384 + offA + 4096); \
    af[1] = *(const bf16x8*)(smem + CB + 16384 + offA + 5120); \
    af[2] = *(const bf16x8*)(smem + CB + 16384 + offA + 6144); \
    af[3] = *(const bf16x8*)(smem + CB + 16384 + offA + 7168); \
    STAGE2(sB + 32, PB + 49152); \
    SBAR(); BAR(); \
    __builtin_amdgcn_s_setprio(1); MFMA16(4); __builtin_amdgcn_s_setprio(0); \
    VM4(); SBAR(); BAR(); \
} while (0)

    STAGE2(gA,      0);
    STAGE2(gB,      32768);
    STAGE2(gA + 32, 16384);
    STAGE2(gB + 32, 49152);
    VM4(); SBAR(); BAR();

    const int T = K >> 6;
    const int T2 = T >> 1;
    #pragma unroll 1
    for (int it = 0; it < T2; ++it) {
        const int t0 = it << 1;
        TILE(0, t0 + 1);
        const int kt2 = (t0 + 2 == T) ? 0 : (t0 + 2);
        TILE(1, kt2);
    }
    asm volatile("s_waitcnt vmcnt(0)" ::: "memory");

    const int er = (l >> 4) * 4;
    const int ec = l & 15;
    #pragma unroll
    for (int mi = 0; mi < 8; ++mi) {
        #pragma unroll
        for (int ni = 0; ni < 4; ++ni) {
            #pragma unroll
            for (int q = 0; q < 4; ++q) {
                int row = m0 + wm * 128 + mi * 16 + er + q;
                int col = n0 + wn * 64  + ni * 16 + ec;
                size_t idx = (size_t)row * N + col;
                float v = acc[mi][ni][q];
                if (MODE == 0) ((unsigned short*)C)[idx] = f32_to_bf16(v);
                else           ((float*)C)[idx] = v;
            }
        }
    }
#undef TILE
#undef MFMA16
#undef STAGE2
#undef VM4
#undef BAR
#undef SBAR
}

extern "C" void kernel_launch(void* const* d_in, const int* in_sizes, int n_in,
                              void* d_out, int out_size, void* d_ws, size_t ws_size,
                              hipStream_t stream)
{
    const float* x  = (const float*)d_in[0];
    const int*   gw = (const int*)  d_in[1];
    const float* gs = (const float*)d_in[2];
    const int*   uw = (const int*)  d_in[3];
    const float* us = (const float*)d_in[4];
    const int*   dw = (const int*)  d_in[5];
    const float* dsc= (const float*)d_in[6];

    // workspace layout (~394 MB)
    char* ws = (char*)d_ws;
    signed char*    Xq  = (signed char*)ws;    ws += (size_t)NTOK * D_MODEL;        // 33.5 MB
    float*          xs  = (float*)ws;          ws += (size_t)NTOK * 4;              // 32 KB
    signed char*    Wg8 = (signed char*)ws;    ws += (size_t)D_FF * D_MODEL;        // 45 MB
    signed char*    Wu8 = (signed char*)ws;    ws += (size_t)D_FF * D_MODEL;        // 45 MB
    unsigned short* Wd  = (unsigned short*)ws; ws += (size_t)D_MODEL * D_FF * 2;    // 90 MB
    unsigned short* H   = (unsigned short*)ws;                                      // 180 MB (gate, then h)

    const long long wtot = (long long)D_FF * D_MODEL;

    hipFuncSetAttribute(reinterpret_cast<const void*>(gemm_i8<0>),
                        hipFuncAttributeMaxDynamicSharedMemorySize, 131072);
    hipFuncSetAttribute(reinterpret_cast<const void*>(gemm_i8<1>),
                        hipFuncAttributeMaxDynamicSharedMemorySize, 131072);
    hipFuncSetAttribute(reinterpret_cast<const void*>(gemm256<2>),
                        hipFuncAttributeMaxDynamicSharedMemorySize, 131072);

    pack_w_kernel   <<<(int)(wtot / 2048), 256, 0, stream>>>(gw, Wg8, wtot);
    pack_w_kernel   <<<(int)(wtot / 2048), 256, 0, stream>>>(uw, Wu8, wtot);
    dequant_w_kernel<<<(int)(wtot / 2048), 256, 0, stream>>>(dw, dsc, Wd, D_FF, wtot);
    quant_x_kernel  <<<NTOK, 256, 0, stream>>>(x, Xq, xs);

    dim3 g1(D_FF / 256, NTOK / 256);     // 43 x 32 = 1376 blocks (%8==0)
    // gate = (Xq @ Wg8^T) * xs*gs -> H (bf16)
    gemm_i8<0><<<g1, 512, 131072, stream>>>(Xq, Wg8, H, nullptr, xs, gs,
                                            NTOK, D_FF, D_MODEL);
    // up GEMM + h = silu(gate)*up -> H (in-place, same-index RMW)
    gemm_i8<1><<<g1, 512, 131072, stream>>>(Xq, Wu8, H, H, xs, us,
                                            NTOK, D_FF, D_MODEL);
    // out = H @ Wd^T -> f32
    dim3 g3(D_MODEL / 256, NTOK / 256);  // 16 x 32 = 512 blocks (%8==0)
    gemm256<2><<<g3, 512, 131072, stream>>>(H, Wd, d_out, NTOK, D_MODEL, D_FF);
}

// Round 7
// 1538.847 us; speedup vs baseline: 6.8311x; 1.0726x over previous
//
#include <hip/hip_runtime.h>

// ---------------------------------------------------------------------------
// SharedOnlyMLP r7: interleaved gate+up int8 GEMM.
//   Wg/Wu packed int8 interleaved in 16-row groups -> ONE i8 GEMM produces
//   gate (ni even) and up (ni odd) in the same wave's accumulators;
//   epilogue computes h = silu(g)*u in-register, writes H once (no gate
//   round-trip). Inner loop identical to r6's proven gemm_i8 (256x256 tile,
//   BK=64, 4-buffer 32KB LDS ring, vmcnt(4), XOR swizzle both sides).
//   Down-proj: r2/r6-proven bf16 gemm256 (BK=64, 2-buffer, 4 phases).
// ---------------------------------------------------------------------------

typedef __attribute__((ext_vector_type(8))) __bf16 bf16x8;
typedef __attribute__((ext_vector_type(4))) float f32x4;
typedef __attribute__((ext_vector_type(8))) unsigned short ushort8;
typedef __attribute__((ext_vector_type(4))) int i32x4;

#define D_MODEL 4096
#define D_FF    11008
#define NTOK    8192

static __device__ __forceinline__ unsigned short f32_to_bf16(float f) {
    union { float f; unsigned u; } v; v.f = f;
    unsigned r = v.u + 0x7fffu + ((v.u >> 16) & 1u);
    return (unsigned short)(r >> 16);
}
static __device__ __forceinline__ void gload_lds16(const void* g, void* l) {
    __builtin_amdgcn_global_load_lds(
        (const __attribute__((address_space(1))) void*)g,
        (__attribute__((address_space(3))) void*)l, 16, 0, 0);
}

// ---- pack gate+up int32 -> interleaved int8 (16-row groups) ----
// out row r (0..2*D_FF): type=(r>>4)&1 (0=gate,1=up), src_row=((r>>5)<<4)+(r&15)
__global__ __launch_bounds__(256)
void pack_gu_kernel(const int* __restrict__ gw, const int* __restrict__ uw,
                    signed char* __restrict__ out)
{
    long long i = ((long long)blockIdx.x * 256 + threadIdx.x) * 8;
    const int r = (int)(i >> 12);           // / D_MODEL (4096)
    const int k = (int)(i & 4095);
    const int src_row = ((r >> 5) << 4) + (r & 15);
    const int* src = ((r >> 4) & 1) ? uw : gw;
    const int* p = src + (size_t)src_row * D_MODEL + k;
    int4 w0 = *(const int4*)(p);
    int4 w1 = *(const int4*)(p + 4);
    union { signed char c[8]; unsigned long long u; } rr;
    rr.c[0] = (signed char)w0.x; rr.c[1] = (signed char)w0.y;
    rr.c[2] = (signed char)w0.z; rr.c[3] = (signed char)w0.w;
    rr.c[4] = (signed char)w1.x; rr.c[5] = (signed char)w1.y;
    rr.c[6] = (signed char)w1.z; rr.c[7] = (signed char)w1.w;
    *(unsigned long long*)(out + i) = rr.u;
}

// ---- weight dequant (down-proj): int32 * s[row] -> bf16 ----
__global__ __launch_bounds__(256)
void dequant_w_kernel(const int* __restrict__ w, const float* __restrict__ s,
                      unsigned short* __restrict__ out, int cols, long long total)
{
    long long i = ((long long)blockIdx.x * 256 + threadIdx.x) * 8;
    if (i >= total) return;
    float sc = s[(int)(i / cols)];
    int4 w0 = *(const int4*)(w + i);
    int4 w1 = *(const int4*)(w + i + 4);
    ushort8 r;
    r[0] = f32_to_bf16((float)w0.x * sc);
    r[1] = f32_to_bf16((float)w0.y * sc);
    r[2] = f32_to_bf16((float)w0.z * sc);
    r[3] = f32_to_bf16((float)w0.w * sc);
    r[4] = f32_to_bf16((float)w1.x * sc);
    r[5] = f32_to_bf16((float)w1.y * sc);
    r[6] = f32_to_bf16((float)w1.z * sc);
    r[7] = f32_to_bf16((float)w1.w * sc);
    *(ushort8*)(out + i) = r;
}

// ---- x: f32 -> per-row int8 + scale ----
__global__ __launch_bounds__(256)
void quant_x_kernel(const float* __restrict__ x, signed char* __restrict__ xq,
                    float* __restrict__ xs)
{
    __shared__ float red[4];
    const int row = blockIdx.x;
    const int t   = threadIdx.x;
    const float* xr = x + (size_t)row * D_MODEL;
    float4 v0 = *(const float4*)(xr + t * 16);
    float4 v1 = *(const float4*)(xr + t * 16 + 4);
    float4 v2 = *(const float4*)(xr + t * 16 + 8);
    float4 v3 = *(const float4*)(xr + t * 16 + 12);
    float m = fabsf(v0.x);
    m = fmaxf(m, fabsf(v0.y)); m = fmaxf(m, fabsf(v0.z)); m = fmaxf(m, fabsf(v0.w));
    m = fmaxf(m, fabsf(v1.x)); m = fmaxf(m, fabsf(v1.y)); m = fmaxf(m, fabsf(v1.z)); m = fmaxf(m, fabsf(v1.w));
    m = fmaxf(m, fabsf(v2.x)); m = fmaxf(m, fabsf(v2.y)); m = fmaxf(m, fabsf(v2.z)); m = fmaxf(m, fabsf(v2.w));
    m = fmaxf(m, fabsf(v3.x)); m = fmaxf(m, fabsf(v3.y)); m = fmaxf(m, fabsf(v3.z)); m = fmaxf(m, fabsf(v3.w));
    #pragma unroll
    for (int o = 32; o > 0; o >>= 1) m = fmaxf(m, __shfl_xor(m, o));
    if ((t & 63) == 0) red[t >> 6] = m;
    __syncthreads();
    m = fmaxf(fmaxf(red[0], red[1]), fmaxf(red[2], red[3]));
    m = fmaxf(m, 1e-20f);
    const float inv = 127.0f / m;
    if (t == 0) xs[row] = m / 127.0f;
    union { signed char c[16]; int4 i; } r;
    #pragma unroll
    for (int j = 0; j < 4; ++j) {
        float4 v = (j == 0) ? v0 : (j == 1) ? v1 : (j == 2) ? v2 : v3;
        r.c[j*4+0] = (signed char)(int)rintf(fminf(fmaxf(v.x*inv,-127.f),127.f));
        r.c[j*4+1] = (signed char)(int)rintf(fminf(fmaxf(v.y*inv,-127.f),127.f));
        r.c[j*4+2] = (signed char)(int)rintf(fminf(fmaxf(v.z*inv,-127.f),127.f));
        r.c[j*4+3] = (signed char)(int)rintf(fminf(fmaxf(v.w*inv,-127.f),127.f));
    }
    *(int4*)(xq + (size_t)row * D_MODEL + t * 16) = r.i;
}

// ---------------------------------------------------------------------------
// Fused gate+up i8 GEMM over interleaved B (2*D_FF rows):
//   h[row][c] = silu(acc_gate * gs[c] * xs[row]) * (acc_up * us[c] * xs[row])
// 256x256 interleaved tile = 128 h-cols. Inner loop = r6 gemm_i8 verbatim.
// ---------------------------------------------------------------------------
__global__ __launch_bounds__(512, 2)
void gemm_i8gu(const signed char* __restrict__ A,
               const signed char* __restrict__ B,   // interleaved [2*D_FF][K]
               unsigned short* __restrict__ H,      // [M][NH]
               const float* __restrict__ xs,
               const float* __restrict__ gs,
               const float* __restrict__ us,
               int M, int NH, int K)
{
    extern __shared__ char smem[];
    const int tid = threadIdx.x;
    const int l   = tid & 63;
    const int w   = tid >> 6;
    const int wm  = w >> 2;
    const int wn  = w & 3;

    const int nbx  = gridDim.x;
    const int nwg  = nbx * gridDim.y;
    const int orig = blockIdx.y * nbx + blockIdx.x;
    const int cpx  = nwg >> 3;
    const int swz  = (orig & 7) * cpx + (orig >> 3);
    const int bn = swz % nbx, bm = swz / nbx;
    const int m0 = bm * 256, n0 = bn * 256;     // n0 over interleaved rows

    // staging: thread t -> row t>>2, 16-B chunk (t&3), source pre-swizzled
    const int st_r = tid >> 2;
    const int st_c = ((tid & 3) ^ ((st_r >> 1) & 3)) << 4;
    const signed char* gA = A + (size_t)(m0 + st_r) * K + st_c;
    const signed char* gB = B + (size_t)(n0 + st_r) * K + st_c;
    const size_t ld128 = (size_t)128 * K;

    // ds_read offsets (swizzled), row stride 64 B
    const int s4v = l >> 4;
    const int rA = wm * 128 + (l & 15);
    const int rB = wn * 64  + (l & 15);
    const int offA = rA * 64 + ((s4v << 4) ^ (((rA >> 1) & 3) << 4));
    const int offB = 16384 + rB * 64 + ((s4v << 4) ^ (((rB >> 1) & 3) << 4));

    i32x4 acc[8][4] = {};
    i32x4 af[4], bfr[4];

#define SBAR()  __builtin_amdgcn_sched_barrier(0)
#define BAR()   __builtin_amdgcn_s_barrier()
#define VM4()   asm volatile("s_waitcnt vmcnt(4)" ::: "memory")

#define ST_A8(SS, NXT) do { \
    const signed char* p_ = gA + ((size_t)(SS) << 6); \
    gload_lds16(p_,         smem + (NXT) + (w << 10)); \
    gload_lds16(p_ + ld128, smem + (NXT) + 8192 + (w << 10)); } while (0)
#define ST_B8(SS, NXT) do { \
    const signed char* p_ = gB + ((size_t)(SS) << 6); \
    gload_lds16(p_,         smem + (NXT) + 16384 + (w << 10)); \
    gload_lds16(p_ + ld128, smem + (NXT) + 16384 + 8192 + (w << 10)); } while (0)

#define MFMA16_I8(MB) do { \
    _Pragma("unroll") \
    for (int mi_ = 0; mi_ < 4; ++mi_) { \
        _Pragma("unroll") \
        for (int ni_ = 0; ni_ < 4; ++ni_) { \
            acc[(MB) + mi_][ni_] = __builtin_amdgcn_mfma_i32_16x16x64_i8( \
                af[mi_], bfr[ni_], acc[(MB) + mi_][ni_], 0, 0, 0); \
        } } } while (0)

#define STEP8(CUR, NXT, SS) do { \
    af[0]  = *(const i32x4*)(smem + (CUR) + offA); \
    af[1]  = *(const i32x4*)(smem + (CUR) + offA + 1024); \
    af[2]  = *(const i32x4*)(smem + (CUR) + offA + 2048); \
    af[3]  = *(const i32x4*)(smem + (CUR) + offA + 3072); \
    bfr[0] = *(const i32x4*)(smem + (CUR) + offB); \
    bfr[1] = *(const i32x4*)(smem + (CUR) + offB + 1024); \
    bfr[2] = *(const i32x4*)(smem + (CUR) + offB + 2048); \
    bfr[3] = *(const i32x4*)(smem + (CUR) + offB + 3072); \
    ST_A8(SS, NXT); \
    SBAR(); BAR(); \
    __builtin_amdgcn_s_setprio(1); MFMA16_I8(0); __builtin_amdgcn_s_setprio(0); \
    SBAR(); BAR(); \
    af[0] = *(const i32x4*)(smem + (CUR) + offA + 4096); \
    af[1] = *(const i32x4*)(smem + (CUR) + offA + 5120); \
    af[2] = *(const i32x4*)(smem + (CUR) + offA + 6144); \
    af[3] = *(const i32x4*)(smem + (CUR) + offA + 7168); \
    ST_B8(SS, NXT); \
    SBAR(); BAR(); \
    __builtin_amdgcn_s_setprio(1); MFMA16_I8(4); __builtin_amdgcn_s_setprio(0); \
    VM4(); SBAR(); BAR(); \
} while (0)

    ST_A8(0, 0);      ST_B8(0, 0);
    ST_A8(1, 32768);  ST_B8(1, 32768);
    VM4(); SBAR(); BAR();

    const int T = K >> 6;            // 64; T%4==0
    #pragma unroll 1
    for (int s = 0; s < T; s += 4) {
        int s2 = s + 2; if (s2 >= T) s2 -= T;
        int s3 = s + 3; if (s3 >= T) s3 -= T;
        int s4 = s + 4; if (s4 >= T) s4 -= T;
        int s5 = s + 5; if (s5 >= T) s5 -= T;
        STEP8(0,     65536, s2);
        STEP8(32768, 98304, s3);
        STEP8(65536, 0,     s4);
        STEP8(98304, 32768, s5);
    }
    asm volatile("s_waitcnt vmcnt(0)" ::: "memory");

    // epilogue: interleaved ni pairs -> h = silu(g)*u
    // interleaved col j = n0 + wn*64 + ni*16 + ec; 16-group parity = ni&1
    // actual h col c = n0/2 + wn*32 + (ni>>1)*16 + ec (same for the pair)
    const int er = (l >> 4) * 4;
    const int ec = l & 15;
    const int hbase = (n0 >> 1) + wn * 32;
    #pragma unroll
    for (int mi = 0; mi < 8; ++mi) {
        const int rowb = m0 + wm * 128 + mi * 16 + er;
        const float4 xsv = *(const float4*)(xs + rowb);
        #pragma unroll
        for (int p = 0; p < 2; ++p) {
            const int c = hbase + p * 16 + ec;
            const float sg = gs[c];
            const float su = us[c];
            #pragma unroll
            for (int q = 0; q < 4; ++q) {
                const float xsc = (q == 0) ? xsv.x : (q == 1) ? xsv.y
                                 : (q == 2) ? xsv.z : xsv.w;
                float g = (float)acc[mi][2*p][q]     * sg * xsc;
                float u = (float)acc[mi][2*p + 1][q] * su * xsc;
                float sig = 1.0f / (1.0f + __expf(-g));
                H[(size_t)(rowb + q) * NH + c] = f32_to_bf16(g * sig * u);
            }
        }
    }
#undef STEP8
#undef MFMA16_I8
#undef ST_A8
#undef ST_B8
#undef VM4
#undef BAR
#undef SBAR
}

// ---------------------------------------------------------------------------
// Down-proj bf16 GEMM — r2/r6-proven structure (BK=64 2-buffer, 4 phases).
// ---------------------------------------------------------------------------
__global__ __launch_bounds__(512, 2)
void gemm256_down(const unsigned short* __restrict__ A,
                  const unsigned short* __restrict__ B,
                  float* __restrict__ C,
                  int M, int N, int K)
{
    extern __shared__ char smem[];
    const int tid = threadIdx.x;
    const int l   = tid & 63;
    const int w   = tid >> 6;
    const int wm  = w >> 2;
    const int wn  = w & 3;

    const int nbx  = gridDim.x;
    const int nwg  = nbx * gridDim.y;
    const int orig = blockIdx.y * nbx + blockIdx.x;
    const int cpx  = nwg >> 3;
    const int swz  = (orig & 7) * cpx + (orig >> 3);
    const int bn = swz % nbx, bm = swz / nbx;
    const int m0 = bm * 256, n0 = bn * 256;

    const int st_r = w * 16 + (l >> 2);
    const int st_c = (((l & 3) ^ ((l >> 3) & 3)) << 3);
    const unsigned short* gA = A + (size_t)(m0 + st_r) * K + st_c;
    const unsigned short* gB = B + (size_t)(n0 + st_r) * K + st_c;
    const size_t ld128 = (size_t)128 * K;

    const int s4v = l >> 4;
    const int rA = wm * 128 + (l & 15);
    const int rB = wn * 64  + (l & 15);
    const int offA = rA * 64 + ((s4v << 4) ^ (((rA >> 1) & 3) << 4));
    const int offB = 32768 + rB * 64 + ((s4v << 4) ^ (((rB >> 1) & 3) << 4));

    f32x4 acc[8][4] = {};
    bf16x8 af[4], bfr[4];

#define SBAR()  __builtin_amdgcn_sched_barrier(0)
#define BAR()   __builtin_amdgcn_s_barrier()
#define VM4()   asm volatile("s_waitcnt vmcnt(4)" ::: "memory")
#define STAGE2(SRC, LOFF) do { \
    gload_lds16((SRC), smem + (LOFF) + (w << 10)); \
    gload_lds16((SRC) + ld128, smem + (LOFF) + 8192 + (w << 10)); } while (0)

#define MFMA16(MB) do { \
    _Pragma("unroll") \
    for (int mi_ = 0; mi_ < 4; ++mi_) { \
        _Pragma("unroll") \
        for (int ni_ = 0; ni_ < 4; ++ni_) { \
            acc[(MB) + mi_][ni_] = __builtin_amdgcn_mfma_f32_16x16x32_bf16( \
                af[mi_], bfr[ni_], acc[(MB) + mi_][ni_], 0, 0, 0); \
        } } } while (0)

#define TILE(DB, KTN) do { \
    const int CB = (DB) * 65536; \
    const int PB = ((DB) ^ 1) * 65536; \
    const unsigned short* sA = gA + ((size_t)(KTN) << 6); \
    const unsigned short* sB = gB + ((size_t)(KTN) << 6); \
    af[0]  = *(const bf16x8*)(smem + CB + offA); \
    af[1]  = *(const bf16x8*)(smem + CB + offA + 1024); \
    af[2]  = *(const bf16x8*)(smem + CB + offA + 2048); \
    af[3]  = *(const bf16x8*)(smem + CB + offA + 3072); \
    bfr[0] = *(const bf16x8*)(smem + CB + offB); \
    bfr[1] = *(const bf16x8*)(smem + CB + offB + 1024); \
    bfr[2] = *(const bf16x8*)(smem + CB + offB + 2048); \
    bfr[3] = *(const bf16x8*)(smem + CB + offB + 3072); \
    STAGE2(sA, PB); \
    SBAR(); BAR(); \
    __builtin_amdgcn_s_setprio(1); MFMA16(0); __builtin_amdgcn_s_setprio(0); \
    SBAR(); BAR(); \
    af[0] = *(const bf16x8*)(smem + CB + offA + 4096); \
    af[1] = *(const bf16x8*)(smem + CB + offA + 5120); \
    af[2] = *(const bf16x8*)(smem + CB + offA + 6144); \
    af[3] = *(const bf16x8*)(smem + CB + offA + 7168); \
    STAGE2(sB, PB + 32768); \
    SBAR(); BAR(); \
    __builtin_amdgcn_s_setprio(1); MFMA16(4); __builtin_amdgcn_s_setprio(0); \
    VM4(); SBAR(); BAR(); \
    af[0]  = *(const bf16x8*)(smem + CB + 16384 + offA); \
    af[1]  = *(const bf16x8*)(smem + CB + 16384 + offA + 1024); \
    af[2]  = *(const bf16x8*)(smem + CB + 16384 + offA + 2048); \
    af[3]  = *(const bf16x8*)(smem + CB + 16384 + offA + 3072); \
    bfr[0] = *(const bf16x8*)(smem + CB + 16384 + offB); \
    bfr[1] = *(const bf16x8*)(smem + CB + 16384 + offB + 1024); \
    bfr[2] = *(const bf16x8*)(smem + CB + 16384 + offB + 2048); \
    bfr[3] = *(const bf16x8*)(smem + CB + 16384 + offB + 3072); \
    STAGE2(sA + 32, PB + 16384); \
    SBAR(); BAR(); \
    __builtin_amdgcn_s_setprio(1); MFMA16(0); __builtin_amdgcn_s_setprio(0); \
    SBAR(); BAR(); \
    af[0] = *(const bf16x8*)(smem + CB + 16384 + offA + 4096); \
    af[1] = *(const bf16x8*)(smem + CB + 16384 + offA + 5120); \
    af[2] = *(const bf16x8*)(smem + CB + 16384 + offA + 6144); \
    af[3] = *(const bf16x8*)(smem + CB + 16384 + offA + 7168); \
    STAGE2(sB + 32, PB + 49152); \
    SBAR(); BAR(); \
    __builtin_amdgcn_s_setprio(1); MFMA16(4); __builtin_amdgcn_s_setprio(0); \
    VM4(); SBAR(); BAR(); \
} while (0)

    STAGE2(gA,      0);
    STAGE2(gB,      32768);
    STAGE2(gA + 32, 16384);
    STAGE2(gB + 32, 49152);
    VM4(); SBAR(); BAR();

    const int T = K >> 6;
    const int T2 = T >> 1;
    #pragma unroll 1
    for (int it = 0; it < T2; ++it) {
        const int t0 = it << 1;
        TILE(0, t0 + 1);
        const int kt2 = (t0 + 2 == T) ? 0 : (t0 + 2);
        TILE(1, kt2);
    }
    asm volatile("s_waitcnt vmcnt(0)" ::: "memory");

    const int er = (l >> 4) * 4;
    const int ec = l & 15;
    #pragma unroll
    for (int mi = 0; mi < 8; ++mi) {
        #pragma unroll
        for (int ni = 0; ni < 4; ++ni) {
            #pragma unroll
            for (int q = 0; q < 4; ++q) {
                int row = m0 + wm * 128 + mi * 16 + er + q;
                int col = n0 + wn * 64  + ni * 16 + ec;
                C[(size_t)row * N + col] = acc[mi][ni][q];
            }
        }
    }
#undef TILE
#undef MFMA16
#undef STAGE2
#undef VM4
#undef BAR
#undef SBAR
}

extern "C" void kernel_launch(void* const* d_in, const int* in_sizes, int n_in,
                              void* d_out, int out_size, void* d_ws, size_t ws_size,
                              hipStream_t stream)
{
    const float* x  = (const float*)d_in[0];
    const int*   gw = (const int*)  d_in[1];
    const float* gs = (const float*)d_in[2];
    const int*   uw = (const int*)  d_in[3];
    const float* us = (const float*)d_in[4];
    const int*   dw = (const int*)  d_in[5];
    const float* dsc= (const float*)d_in[6];

    // workspace layout (~394 MB)
    char* ws = (char*)d_ws;
    signed char*    Xq   = (signed char*)ws;    ws += (size_t)NTOK * D_MODEL;          // 33.5 MB
    float*          xs   = (float*)ws;          ws += (size_t)NTOK * 4;                // 32 KB
    signed char*    Wgu8 = (signed char*)ws;    ws += (size_t)2 * D_FF * D_MODEL;      // 90 MB
    unsigned short* Wd   = (unsigned short*)ws; ws += (size_t)D_MODEL * D_FF * 2;      // 90 MB
    unsigned short* H    = (unsigned short*)ws;                                        // 180 MB

    const long long wtot  = (long long)D_FF * D_MODEL;
    const long long gutot = 2LL * wtot;

    hipFuncSetAttribute(reinterpret_cast<const void*>(gemm_i8gu),
                        hipFuncAttributeMaxDynamicSharedMemorySize, 131072);
    hipFuncSetAttribute(reinterpret_cast<const void*>(gemm256_down),
                        hipFuncAttributeMaxDynamicSharedMemorySize, 131072);

    pack_gu_kernel  <<<(int)(gutot / 2048), 256, 0, stream>>>(gw, uw, Wgu8);
    dequant_w_kernel<<<(int)(wtot  / 2048), 256, 0, stream>>>(dw, dsc, Wd, D_FF, wtot);
    quant_x_kernel  <<<NTOK, 256, 0, stream>>>(x, Xq, xs);

    // fused gate+up: H = silu(Xq@Wg^T * gs*xs) * (Xq@Wu^T * us*xs)
    dim3 g1(2 * D_FF / 256, NTOK / 256);   // 86 x 32 = 2752 blocks (%8==0)
    gemm_i8gu<<<g1, 512, 131072, stream>>>(Xq, Wgu8, H, xs, gs, us,
                                           NTOK, D_FF, D_MODEL);

    // out = H @ Wd^T -> f32
    dim3 g3(D_MODEL / 256, NTOK / 256);    // 16 x 32 = 512 blocks (%8==0)
    gemm256_down<<<g3, 512, 131072, stream>>>(H, Wd, (float*)d_out,
                                              NTOK, D_MODEL, D_FF);
}